// Round 7
// baseline (174.488 us; speedup 1.0000x reference)
//
#include <hip/hip_runtime.h>

// Problem constants
#define BATCH 32
#define NNODE 4096
#define CIN 32
#define COUT 64
#define KDEG 5
#define POOL 4
#define NNZ_E 65536
#define BC (BATCH * CIN)         // 1024 elems per node-row
#define TBF ((size_t)NNODE * BC) // elems per Chebyshev level (bf16 storage)
#define CAP 64                   // fixed bucket capacity per row (avg degree 16)

typedef short s16x8 __attribute__((ext_vector_type(8)));
typedef float f32x4 __attribute__((ext_vector_type(4)));
typedef unsigned long long u64;

// float -> bf16 bits, round-to-nearest-even
__device__ __forceinline__ unsigned short f2bf(float f) {
    union { float f; unsigned int u; } v; v.f = f;
    unsigned int u = v.u;
    u += 0x7fffu + ((u >> 16) & 1u);
    return (unsigned short)(u >> 16);
}
__device__ __forceinline__ float bf2f(unsigned short b) {
    union { float f; unsigned int u; } v; v.u = ((unsigned int)b) << 16;
    return v.f;
}
__device__ __forceinline__ u64 pack4(float a, float b, float c, float d) {
    return (u64)f2bf(a) | ((u64)f2bf(b) << 16) | ((u64)f2bf(c) << 32) | ((u64)f2bf(d) << 48);
}

// ---------------- prep2: transpose + W pack + capacity-bucket edge scatter -------
// (verified) Row r's edges land in es[r*64 .. r*64+cnt[r]) in arbitrary order
// (summation commutative). cnt zeroed by the preceding 16 KB memset.

__global__ void prep2_kernel(const float* __restrict__ x, unsigned short* __restrict__ t0,
                             const int* __restrict__ erow, const int* __restrict__ ecol,
                             const float* __restrict__ eval,
                             int* __restrict__ cnt, int2* __restrict__ es,
                             const float* __restrict__ W, unsigned short* __restrict__ WB) {
    int idx = blockIdx.x * 256 + threadIdx.x;   // [0, 1048576)
    // transpose [B][N][C] fp32 -> [N][B*C] bf16, 4 elems per thread
    int n   = idx >> 8;
    int rem = idx & 255;
    int b   = rem >> 3;
    int c4  = rem & 7;
    float4 v = ((const float4*)x)[(b * NNODE + n) * 8 + c4];
    ((u64*)t0)[idx] = pack4(v.x, v.y, v.z, v.w);

    if (idx < NNZ_E) {
        int r = erow[idx];
        int pos = atomicAdd(&cnt[r], 1);
        if (pos < CAP)
            es[(r << 6) + pos] = make_int2(ecol[idx], __float_as_int(eval[idx]));
    }

    if (idx < KDEG * COUT * CIN) {
        int c = idx & 31;
        int rest = idx >> 5;
        int o = rest & 63;
        int k = rest >> 6;
        // WB[k][o][c] : B-fragment order for mfma_16x16x32 (lane nn=o, kk=c)
        WB[idx] = f2bf(W[(c * KDEG + k) * COUT + o]);
    }
}

// ---------------- one (row, slice) unit of Chebyshev SpMM -- 4-ep layout --------
// (verified round 5/6) Lanes = 4 edge-groups (ep = lane>>4) x 16 cols of 16B.
// One 4-deep iteration puts all 16 edges of an average row in flight at once.
// Gather coalesced: 16 lanes x 16B = 256B contiguous per edge. sub loads NORMAL
// (keeps t_{k-1} slices L2-resident for the GEMM A-reads).
// Returns the packed bf16x8 (16B) result on lanes 0..15 (ep==0).

__device__ __forceinline__ s16x8 spmm_row4(
        const unsigned short* in, const unsigned short* sub,
        float scale, int has_sub, const int* cnt, const int2* es,
        int r, int s, int lane) {
    int ep  = lane >> 4;               // edge-group 0..3
    int c16 = lane & 15;               // 16B col within slice (16 x 16B = 256B)
    const s16x8* in16 = (const s16x8*)in;   // row stride = 128 x 16B

    int deg = cnt[r]; deg = deg > CAP ? CAP : deg;
    int beg = r << 6, end = beg + deg;

    float acc[8] = {0.f,0.f,0.f,0.f,0.f,0.f,0.f,0.f};

    for (int base = beg + ep; base < end; base += 16) {
        float vv[4];
        s16x8 xx[4];
#pragma unroll
        for (int j = 0; j < 4; j++) {
            int idx = base + 4 * j;
            int src = idx < end ? idx : beg;   // beg valid: loop was entered
            int2 e = es[src];
            vv[j] = idx < end ? __int_as_float(e.y) : 0.f;
            xx[j] = in16[(size_t)e.x * 128 + s * 16 + c16];
        }
#pragma unroll
        for (int j = 0; j < 4; j++)
#pragma unroll
            for (int t = 0; t < 8; t++)
                acc[t] += vv[j] * bf2f((unsigned short)xx[j][t]);
    }

    // reduce across the 4 edge-groups (lane^16 then lane^32)
#pragma unroll
    for (int t = 0; t < 8; t++) {
        acc[t] += __shfl_xor(acc[t], 16);
        acc[t] += __shfl_xor(acc[t], 32);
    }

    union { u64 u[2]; s16x8 v; } res;
    res.u[0] = 0; res.u[1] = 0;
    if (ep == 0) {
        size_t oi = (size_t)r * 128 + s * 16 + c16;   // 16B units
        float rr[8];
        if (has_sub) {
            u64 sv0 = ((const u64*)sub)[2 * oi];
            u64 sv1 = ((const u64*)sub)[2 * oi + 1];
#pragma unroll
            for (int t = 0; t < 4; t++)
                rr[t] = scale * acc[t] - bf2f((unsigned short)(sv0 >> (16 * t)));
#pragma unroll
            for (int t = 0; t < 4; t++)
                rr[4 + t] = scale * acc[4 + t] - bf2f((unsigned short)(sv1 >> (16 * t)));
        } else {
#pragma unroll
            for (int t = 0; t < 8; t++) rr[t] = acc[t];
        }
        res.u[0] = pack4(rr[0], rr[1], rr[2], rr[3]);
        res.u[1] = pack4(rr[4], rr[5], rr[6], rr[7]);
    }
    return res.v;
}

// ---------------- standalone per-level SpMM (levels 1-3) ----------------
// grid = NNODE*2 = 8192 blocks of 256; block = 4 rows x 1 slice
// (slice = bx&7 = XCD -- the pinning that makes gathers L2-local).

__global__ __launch_bounds__(256, 8) void spmm_lvl_kernel(
        const unsigned short* __restrict__ in, const unsigned short* __restrict__ sub,
        unsigned short* __restrict__ out, float scale, int has_sub,
        const int* __restrict__ cnt, const int2* __restrict__ es) {
    int bx    = blockIdx.x;
    int slice = bx & 7;
    int rg    = bx >> 3;
    int wave  = threadIdx.x >> 6;
    int lane  = threadIdx.x & 63;
    int r     = rg * 4 + wave;

    s16x8 res = spmm_row4(in, sub, scale, has_sub, cnt, es, r, slice, lane);
    if (lane < 16)
        ((s16x8*)out)[(size_t)r * 128 + slice * 16 + lane] = res;  // keep slice in L2
}

// ---------------- merged: spmm level 4 + MFMA GEMM + bias + ReLU + maxpool ------
// SAME grid/block as spmm_lvl (8192 x 256, slice = bid&7, 1 row/wave in phase 1)
// -- the geometry rounds 5/6 proved matters. The GEMM tile is reshaped to fit
// the block's own data: MFMA M = 16 (node,batch) pairs = block's 4 rows x the
// slice's 4 batches; the block's own t4 (4 rows x 256B) covers exactly the k=4
// A-frags -> t4 lives in LDS only (saves 8MB write + 8MB read + 1 boundary).
// D layout: row = q*4+reg = (batch q, node-offset reg) -> pool = in-lane max
// over the 4 acc regs; col = lane&15 = output channel (verified mapping).
// Each wave handles 16 output channels (oc = wave).

__global__ __launch_bounds__(256, 8) void spmm4_gemm_kernel(
        const unsigned short* __restrict__ t3, const unsigned short* __restrict__ t2,
        const unsigned short* __restrict__ tbase, const int* __restrict__ cnt,
        const int2* __restrict__ es, const unsigned short* __restrict__ WB,
        const float* __restrict__ bias, float* __restrict__ out) {
    __shared__ s16x8 t4l[4][17];           // 4 rows x 16 chunks of 16B (+1 pad)

    int bx    = blockIdx.x;
    int s     = bx & 7;                    // slice == XCD
    int rg    = bx >> 3;                   // row group of 4
    int wv    = threadIdx.x >> 6;
    int lane  = threadIdx.x & 63;

    // ---- phase 1: t4 row rg*4+wv, slice s -> LDS (identical to spmm_lvl) ----
    {
        int r = rg * 4 + wv;
        s16x8 res = spmm_row4(t3, t2, 2.0f, 1, cnt, es, r, s, lane);
        if (lane < 16)
            t4l[wv][lane] = res;
    }
    __syncthreads();

    // ---- phase 2: GEMM for M = (4 nodes x 4 batches), N = 16 outs per wave ----
    int m  = lane & 15;                    // A-row index (M)
    int q  = lane >> 4;                    // k-half for A/B frags; batch for D
    int dn = m & 3;                        // node offset within pool group
    int bs = m >> 2;                       // batch offset within slice
    int n  = rg * 4 + dn;
    int b  = s * 4 + bs;                   // b>>2 == slice -> A-reads XCD-local

    f32x4 acc = {0.f, 0.f, 0.f, 0.f};
    const unsigned short* abase = tbase + (size_t)n * BC + b * CIN + q * 8;
    const unsigned short* wbase = WB + (wv * 16 + m) * 32 + q * 8;

#pragma unroll
    for (int kc = 0; kc < 4; kc++) {       // k=0..3 from global (t0..t3, L2-warm)
        s16x8 a  = *(const s16x8*)(abase + (size_t)kc * TBF);
        s16x8 bf = *(const s16x8*)(wbase + (kc * 64) * 32);
        acc = __builtin_amdgcn_mfma_f32_16x16x32_bf16(a, bf, acc, 0, 0, 0);
    }
    {   // k=4 from LDS: row dn, chunk = bs*4+q (chunk c16 covers elems c16*8)
        s16x8 a  = t4l[dn][bs * 4 + q];
        s16x8 bf = *(const s16x8*)(wbase + (4 * 64) * 32);
        acc = __builtin_amdgcn_mfma_f32_16x16x32_bf16(a, bf, acc, 0, 0, 0);
    }

    // bias + ReLU + maxpool: lane = (batch 4s+q, channel wv*16+m); regs = 4 nodes
    float bi = bias[wv * 16 + m];
    float r0 = acc[0] + bi; r0 = r0 > 0.f ? r0 : 0.f;
    float r1 = acc[1] + bi; r1 = r1 > 0.f ? r1 : 0.f;
    float r2 = acc[2] + bi; r2 = r2 > 0.f ? r2 : 0.f;
    float r3 = acc[3] + bi; r3 = r3 > 0.f ? r3 : 0.f;
    float mx = r0 > r1 ? r0 : r1;
    mx = mx > r2 ? mx : r2;
    mx = mx > r3 ? mx : r3;
    out[((size_t)(s * 4 + q) * (NNODE / POOL) + rg) * COUT + wv * 16 + m] = mx;
}

// ---------------- launch: 6 dispatches ----------------

extern "C" void kernel_launch(void* const* d_in, const int* in_sizes, int n_in,
                              void* d_out, int out_size, void* d_ws, size_t ws_size,
                              hipStream_t stream) {
    const float* x    = (const float*)d_in[0];
    const float* eval = (const float*)d_in[1];
    const float* W    = (const float*)d_in[2];
    const float* bias = (const float*)d_in[3];
    const int*   erow = (const int*)d_in[4];
    const int*   ecol = (const int*)d_in[5];
    float* out = (float*)d_out;

    char* base = (char*)d_ws;
    unsigned short* tb = (unsigned short*)base;     // 4 levels x 8 MB (bf16); t4 in LDS
    unsigned short* t0 = tb;
    unsigned short* t1 = tb + 1 * TBF;
    unsigned short* t2 = tb + 2 * TBF;
    unsigned short* t3 = tb + 3 * TBF;

    size_t off = 5 * TBF * sizeof(unsigned short);  // keep layout (t4 slot unused)
    int2* es = (int2*)(base + off);  off += (size_t)NNODE * CAP * sizeof(int2);
    int* cnt = (int*)(base + off);   off += (size_t)NNODE * sizeof(int);
    off += 32 * sizeof(int);                        // legacy bar slot, unused
    off = (off + 63) & ~(size_t)63;
    unsigned short* WB = (unsigned short*)(base + off);

    // zero scatter cursors (d_ws re-poisoned every call -> rebuild each call)
    hipMemsetAsync(cnt, 0, NNODE * sizeof(int), stream);

    // transpose + W pack + bucket scatter
    prep2_kernel<<<TBF / 4 / 256, 256, 0, stream>>>(x, t0, erow, ecol, eval,
                                                    cnt, es, W, WB);

    // Chebyshev levels 1-3, column-sliced, bf16 storage / fp32 accumulate
    spmm_lvl_kernel<<<NNODE * 2, 256, 0, stream>>>(t0, nullptr, t1, 1.0f, 0, cnt, es);
    spmm_lvl_kernel<<<NNODE * 2, 256, 0, stream>>>(t1, t0, t2, 2.0f, 1, cnt, es);
    spmm_lvl_kernel<<<NNODE * 2, 256, 0, stream>>>(t2, t1, t3, 2.0f, 1, cnt, es);

    // level 4 + GEMM + bias + ReLU + maxpool, fused with spmm_lvl geometry
    spmm4_gemm_kernel<<<NNODE * 2, 256, 0, stream>>>(t3, t2, tb, cnt, es, WB,
                                                     bias, out);
}

// Round 10
// 159.743 us; speedup vs baseline: 1.0923x; 1.0923x over previous
//
#include <hip/hip_runtime.h>

// Problem constants
#define BATCH 32
#define NNODE 4096
#define CIN 32
#define COUT 64
#define KDEG 5
#define POOL 4
#define NNZ_E 65536
#define BC (BATCH * CIN)         // 1024 elems per node-row
#define TBF ((size_t)NNODE * BC) // elems per Chebyshev level (bf16 storage)
#define CAP 64                   // fixed bucket capacity per row (avg degree 16)

typedef short s16x8 __attribute__((ext_vector_type(8)));
typedef float f32x4 __attribute__((ext_vector_type(4)));
typedef unsigned long long u64;

// float -> bf16 bits, round-to-nearest-even
__device__ __forceinline__ unsigned short f2bf(float f) {
    union { float f; unsigned int u; } v; v.f = f;
    unsigned int u = v.u;
    u += 0x7fffu + ((u >> 16) & 1u);
    return (unsigned short)(u >> 16);
}
__device__ __forceinline__ float bf2f(unsigned short b) {
    union { float f; unsigned int u; } v; v.u = ((unsigned int)b) << 16;
    return v.f;
}
__device__ __forceinline__ u64 pack4(float a, float b, float c, float d) {
    return (u64)f2bf(a) | ((u64)f2bf(b) << 16) | ((u64)f2bf(c) << 32) | ((u64)f2bf(d) << 48);
}

// ---------------- prep2: transpose + W pack (frag-major) + edge scatter ---------
// Row r's edges land in es[r*64 .. r*64+cnt[r]) in arbitrary order (summation
// commutative). cnt zeroed by the preceding 16 KB memset.
// Weights packed FRAG-MAJOR (WBF, verified bijective): for MFMA frag (k,ot),
// lane l = q*16+m holds W rows o=ot*16+m, cols c=q*8..q*8+7 at
// WBF[((k*4+ot)*64+l)*8 + (c&7)] -- lets the GEMM stage all frags to LDS
// coalesced and read conflict-free (lane x 16B).

__global__ void prep2_kernel(const float* __restrict__ x, unsigned short* __restrict__ t0,
                             const int* __restrict__ erow, const int* __restrict__ ecol,
                             const float* __restrict__ eval,
                             int* __restrict__ cnt, int2* __restrict__ es,
                             const float* __restrict__ W, unsigned short* __restrict__ WBF) {
    int idx = blockIdx.x * 256 + threadIdx.x;   // [0, 1048576)
    // transpose [B][N][C] fp32 -> [N][B*C] bf16, 4 elems per thread
    int n   = idx >> 8;
    int rem = idx & 255;
    int b   = rem >> 3;
    int c4  = rem & 7;
    float4 v = ((const float4*)x)[(b * NNODE + n) * 8 + c4];
    ((u64*)t0)[idx] = pack4(v.x, v.y, v.z, v.w);

    if (idx < NNZ_E) {
        int r = erow[idx];
        int pos = atomicAdd(&cnt[r], 1);
        if (pos < CAP)
            es[(r << 6) + pos] = make_int2(ecol[idx], __float_as_int(eval[idx]));
    }

    if (idx < KDEG * COUT * CIN) {
        int c = idx & 31;
        int rest = idx >> 5;
        int o = rest & 63;
        int k = rest >> 6;
        // frag-major slot: group g = k*4 + (o>>4), lane = (c>>3)*16 + (o&15)
        int g    = k * 4 + (o >> 4);
        int lane = ((c >> 3) << 4) + (o & 15);
        WBF[(size_t)(g * 64 + lane) * 8 + (c & 7)] =
            f2bf(W[(c * KDEG + k) * COUT + o]);
    }
}

// ---------------- one (row, slice) unit of Chebyshev SpMM -- 4-ep layout --------
// EXACT round-6 verified body (166.3us run): direct per-lane es loads, plain u64
// sub loads. (Round 8's es-preload+__shfl broadcast produced poison-sensitive
// wrong results -- reverted, documented as unsafe.)
// Lanes = 4 edge-groups (ep = lane>>4) x 16 cols of 16B; one 4-deep iteration
// puts all 16 edges of an average row in flight. Gather coalesced: 16 lanes x
// 16B = 256B contiguous per edge. sub loads NORMAL (keeps t_{k-1} L2-resident
// for the GEMM A-reads). Returns packed bf16x8 on lanes 0..15 (ep==0).

__device__ __forceinline__ s16x8 spmm_row4(
        const unsigned short* in, const unsigned short* sub,
        float scale, int has_sub, const int* cnt, const int2* es,
        int r, int s, int lane) {
    int ep  = lane >> 4;               // edge-group 0..3
    int c16 = lane & 15;               // 16B col within slice (16 x 16B = 256B)
    const s16x8* in16 = (const s16x8*)in;   // row stride = 128 x 16B

    int deg = cnt[r]; deg = deg > CAP ? CAP : deg;
    int beg = r << 6, end = beg + deg;

    float acc[8] = {0.f,0.f,0.f,0.f,0.f,0.f,0.f,0.f};

    for (int base = beg + ep; base < end; base += 16) {
        float vv[4];
        s16x8 xx[4];
#pragma unroll
        for (int j = 0; j < 4; j++) {
            int idx = base + 4 * j;
            int src = idx < end ? idx : beg;   // beg valid: loop was entered
            int2 e = es[src];
            vv[j] = idx < end ? __int_as_float(e.y) : 0.f;
            xx[j] = in16[(size_t)e.x * 128 + s * 16 + c16];
        }
#pragma unroll
        for (int j = 0; j < 4; j++)
#pragma unroll
            for (int t = 0; t < 8; t++)
                acc[t] += vv[j] * bf2f((unsigned short)xx[j][t]);
    }

    // reduce across the 4 edge-groups (lane^16 then lane^32)
#pragma unroll
    for (int t = 0; t < 8; t++) {
        acc[t] += __shfl_xor(acc[t], 16);
        acc[t] += __shfl_xor(acc[t], 32);
    }

    union { u64 u[2]; s16x8 v; } res;
    res.u[0] = 0; res.u[1] = 0;
    if (ep == 0) {
        size_t oi = (size_t)r * 128 + s * 16 + c16;   // 16B units
        float rr[8];
        if (has_sub) {
            u64 sv0 = ((const u64*)sub)[2 * oi];
            u64 sv1 = ((const u64*)sub)[2 * oi + 1];
#pragma unroll
            for (int t = 0; t < 4; t++)
                rr[t] = scale * acc[t] - bf2f((unsigned short)(sv0 >> (16 * t)));
#pragma unroll
            for (int t = 0; t < 4; t++)
                rr[4 + t] = scale * acc[4 + t] - bf2f((unsigned short)(sv1 >> (16 * t)));
        } else {
#pragma unroll
            for (int t = 0; t < 8; t++) rr[t] = acc[t];
        }
        res.u[0] = pack4(rr[0], rr[1], rr[2], rr[3]);
        res.u[1] = pack4(rr[4], rr[5], rr[6], rr[7]);
    }
    return res.v;
}

// ---------------- standalone per-level SpMM (levels 1-4) ----------------
// grid = NNODE*2 = 8192 blocks of 256; block = 4 rows x 1 slice
// (slice = bx&7 = XCD -- the pinning that makes gathers L2-local).

__global__ __launch_bounds__(256, 8) void spmm_lvl_kernel(
        const unsigned short* __restrict__ in, const unsigned short* __restrict__ sub,
        unsigned short* __restrict__ out, float scale, int has_sub,
        const int* __restrict__ cnt, const int2* __restrict__ es) {
    int bx    = blockIdx.x;
    int slice = bx & 7;
    int rg    = bx >> 3;
    int wave  = threadIdx.x >> 6;
    int lane  = threadIdx.x & 63;
    int r     = rg * 4 + wave;

    s16x8 res = spmm_row4(in, sub, scale, has_sub, cnt, es, r, slice, lane);
    if (lane < 16)
        ((s16x8*)out)[(size_t)r * 128 + slice * 16 + lane] = res;  // keep slice in L2
}

// ---------------- MFMA GEMM + bias + ReLU + maxpool (round-0 math) -------------
// B-frags staged once per block into LDS from frag-major WBF (coalesced), then
// read conflict-free as lane x 16B ds_read_b128. Removes the ~320 redundant TA
// line-lookups/wave of the old strided WB loads (WB identical across all 8192
// waves -- pure waste). A-loads / D-layout unchanged from the verified round-0
// kernel.

__global__ __launch_bounds__(256) void gemm_mfma_pool_kernel(
        const unsigned short* __restrict__ tbase, const unsigned short* __restrict__ WBF,
        const float* __restrict__ bias, float* __restrict__ out) {
    __shared__ s16x8 wlds[20][64];         // 20 KB: frag (k*4+ot) x lane

    int tid  = threadIdx.x;
    int wv   = tid >> 6;
    int lane = tid & 63;

    // stage all 20 B-frags (coalesced 1 KB per wave-instr, 5 per wave)
#pragma unroll
    for (int p = 0; p < 5; p++) {
        int g = wv * 5 + p;
        wlds[g][lane] = ((const s16x8*)WBF)[g * 64 + lane];
    }
    __syncthreads();

    int gtid = blockIdx.x * 256 + tid;
    int wid  = gtid >> 6;            // [0, 8192)
    int b    = wid >> 8;             // [0, 32)
    int n0   = (wid & 255) << 4;     // node tile base
    int m    = lane & 15;
    int q    = lane >> 4;

    f32x4 acc[4] = {{0.f,0.f,0.f,0.f},{0.f,0.f,0.f,0.f},
                    {0.f,0.f,0.f,0.f},{0.f,0.f,0.f,0.f}};

    const unsigned short* abase = tbase + (size_t)(n0 + m) * BC + b * CIN + q * 8;

#pragma unroll
    for (int k = 0; k < KDEG; k++) {
        s16x8 a = *(const s16x8*)(abase + (size_t)k * TBF);
#pragma unroll
        for (int ot = 0; ot < 4; ot++) {
            s16x8 bf = wlds[k * 4 + ot][lane];
            acc[ot] = __builtin_amdgcn_mfma_f32_16x16x32_bf16(a, bf, acc[ot], 0, 0, 0);
        }
    }

    size_t orow = ((size_t)b * (NNODE / POOL) + (n0 >> 2) + q) * COUT;
#pragma unroll
    for (int ot = 0; ot < 4; ot++) {
        float bi = bias[ot * 16 + m];
        float r0 = acc[ot][0] + bi; r0 = r0 > 0.f ? r0 : 0.f;
        float r1 = acc[ot][1] + bi; r1 = r1 > 0.f ? r1 : 0.f;
        float r2 = acc[ot][2] + bi; r2 = r2 > 0.f ? r2 : 0.f;
        float r3 = acc[ot][3] + bi; r3 = r3 > 0.f ? r3 : 0.f;
        float mx = r0 > r1 ? r0 : r1;
        mx = mx > r2 ? mx : r2;
        mx = mx > r3 ? mx : r3;
        out[orow + ot * 16 + m] = mx;
    }
}

// ---------------- launch: 7 dispatches ----------------

extern "C" void kernel_launch(void* const* d_in, const int* in_sizes, int n_in,
                              void* d_out, int out_size, void* d_ws, size_t ws_size,
                              hipStream_t stream) {
    const float* x    = (const float*)d_in[0];
    const float* eval = (const float*)d_in[1];
    const float* W    = (const float*)d_in[2];
    const float* bias = (const float*)d_in[3];
    const int*   erow = (const int*)d_in[4];
    const int*   ecol = (const int*)d_in[5];
    float* out = (float*)d_out;

    char* base = (char*)d_ws;
    unsigned short* tb = (unsigned short*)base;     // 5 levels x 8 MB (bf16)
    unsigned short* t0 = tb;
    unsigned short* t1 = tb + 1 * TBF;
    unsigned short* t2 = tb + 2 * TBF;
    unsigned short* t3 = tb + 3 * TBF;
    unsigned short* t4 = tb + 4 * TBF;

    size_t off = 5 * TBF * sizeof(unsigned short);
    int2* es = (int2*)(base + off);  off += (size_t)NNODE * CAP * sizeof(int2);
    int* cnt = (int*)(base + off);   off += (size_t)NNODE * sizeof(int);
    off += 32 * sizeof(int);                        // legacy bar slot, unused
    off = (off + 63) & ~(size_t)63;
    unsigned short* WBF = (unsigned short*)(base + off);

    // zero scatter cursors (d_ws re-poisoned every call -> rebuild each call)
    hipMemsetAsync(cnt, 0, NNODE * sizeof(int), stream);

    // transpose + frag-major W pack + bucket scatter
    prep2_kernel<<<TBF / 4 / 256, 256, 0, stream>>>(x, t0, erow, ecol, eval,
                                                    cnt, es, W, WBF);

    // Chebyshev levels 1-4, column-sliced, bf16 storage / fp32 accumulate
    spmm_lvl_kernel<<<NNODE * 2, 256, 0, stream>>>(t0, nullptr, t1, 1.0f, 0, cnt, es);
    spmm_lvl_kernel<<<NNODE * 2, 256, 0, stream>>>(t1, t0, t2, 2.0f, 1, cnt, es);
    spmm_lvl_kernel<<<NNODE * 2, 256, 0, stream>>>(t2, t1, t3, 2.0f, 1, cnt, es);
    spmm_lvl_kernel<<<NNODE * 2, 256, 0, stream>>>(t3, t2, t4, 2.0f, 1, cnt, es);

    // MFMA GEMM + bias + relu + maxpool (B-frags via LDS)
    gemm_mfma_pool_kernel<<<(BATCH * (NNODE / 16) * 64) / 256, 256, 0, stream>>>(
        tb, WBF, bias, out);
}